// Round 3
// baseline (140.664 us; speedup 1.0000x reference)
//
#include <hip/hip_runtime.h>

#define KCODES 512
#define DIM    64
#define NVEC   65536          // 64 * 32 * 32
#define TAU    0.1f

typedef __attribute__((ext_vector_type(8))) short   short8;  // 8 bf16 = 4 VGPRs
typedef __attribute__((ext_vector_type(4))) float   f32x4;

__device__ __forceinline__ unsigned short f2bf(float f) {    // fp32 -> bf16 RNE
    unsigned int u = __builtin_bit_cast(unsigned int, f);
    u += 0x7fffu + ((u >> 16) & 1u);
    return (unsigned short)(u >> 16);
}

// ---------------------------------------------------------------------------
// Prep (fused): one block per code. Split codebook row into bf16 hi(trunc)/lo
// and reduce e2[k] = ||e_k||^2 in fp64.
// ---------------------------------------------------------------------------
__global__ void prep_kernel(const float* __restrict__ cb,
                            unsigned short* __restrict__ cbh,
                            unsigned short* __restrict__ cbl,
                            float* __restrict__ e2) {
    const int k = blockIdx.x, d = threadIdx.x;
    const int e = k * DIM + d;
    float v = cb[e];
    unsigned int u = __builtin_bit_cast(unsigned int, v);
    float hi = __builtin_bit_cast(float, u & 0xFFFF0000u);
    cbh[e] = (unsigned short)(u >> 16);
    cbl[e] = f2bf(v - hi);
    double p = (double)v * (double)v;
#pragma unroll
    for (int off = 32; off > 0; off >>= 1) p += __shfl_down(p, off, 64);
    if (d == 0) e2[k] = (float)p;
}

// ---------------------------------------------------------------------------
// Main: block = 32 vectors, 4 waves. Wave w: vector-group (w>>1) of 16,
// code-half (w&1) of 256. Grid = NVEC/32 = 2048 blocks -> 8 blocks/CU.
// dist-rank = e2[k] - 2*x.e  via 3-term bf16 MFMA; top-2 + fp64 tie resolve.
// ---------------------------------------------------------------------------
__launch_bounds__(256, 8)
__global__ void vq_main(const float* __restrict__ x,
                        const float* __restrict__ cb,
                        const unsigned short* __restrict__ cbh,
                        const unsigned short* __restrict__ cbl,
                        const float* __restrict__ e2g,
                        float* __restrict__ out) {
    __shared__ float s_f1[2][32], s_f2[2][32];
    __shared__ int   s_i1[2][32], s_i2[2][32];
    __shared__ int   s_win[32];

    const int tid   = threadIdx.x;
    const int wave  = tid >> 6;
    const int lane  = tid & 63;
    const int vgrp  = wave >> 1;     // vector group: n 0..15 or 16..31
    const int chalf = wave & 1;      // code half: k 0..255 or 256..511
    const int quad  = lane >> 4;
    const int l16   = lane & 15;

    const int v0    = blockIdx.x * 32;
    const int b     = v0 >> 10;
    const int nbase = v0 & 1023;
    const float* xb = x + (size_t)b * 65536;

    // ---- B fragments: B[k=d][n=l16] for d = quad*8+j (+32*ko), hi/lo -------
    short8 Bh[2], Bl[2];
    {
        const int n_g = nbase + vgrp * 16 + l16;
#pragma unroll
        for (int ko = 0; ko < 2; ++ko) {
#pragma unroll
            for (int j = 0; j < 8; ++j) {
                const int d = quad * 8 + j + ko * 32;
                float f = xb[(size_t)d * 1024 + n_g];
                unsigned int u = __builtin_bit_cast(unsigned int, f);
                float hi = __builtin_bit_cast(float, u & 0xFFFF0000u);
                Bh[ko][j] = (short)(u >> 16);
                Bl[ko][j] = (short)f2bf(f - hi);
            }
        }
    }

    // ---- running top-2 over this wave's 256 codes --------------------------
    float f1 = 3.4e38f, f2_ = 3.4e38f;
    int   i1 = 0,       i2_ = 0;

    for (int tile = 0; tile < 16; ++tile) {
        const int codebase = chalf * 256 + tile * 16;
        const unsigned short* arow = cbh + ((size_t)(codebase + l16)) * DIM + quad * 8;
        const unsigned short* lrow = cbl + ((size_t)(codebase + l16)) * DIM + quad * 8;
        short8 Ah0 = *(const short8*)(arow);
        short8 Ah1 = *(const short8*)(arow + 32);
        short8 Al0 = *(const short8*)(lrow);
        short8 Al1 = *(const short8*)(lrow + 32);
        f32x4 e2v  = *(const f32x4*)(e2g + codebase + quad * 4);

        f32x4 aa = {0.f, 0.f, 0.f, 0.f};
        f32x4 ab = {0.f, 0.f, 0.f, 0.f};
        aa = __builtin_amdgcn_mfma_f32_16x16x32_bf16(Ah0, Bh[0], aa, 0, 0, 0);
        ab = __builtin_amdgcn_mfma_f32_16x16x32_bf16(Ah1, Bh[1], ab, 0, 0, 0);
        aa = __builtin_amdgcn_mfma_f32_16x16x32_bf16(Ah0, Bl[0], aa, 0, 0, 0);
        ab = __builtin_amdgcn_mfma_f32_16x16x32_bf16(Ah1, Bl[1], ab, 0, 0, 0);
        aa = __builtin_amdgcn_mfma_f32_16x16x32_bf16(Al0, Bh[0], aa, 0, 0, 0);
        ab = __builtin_amdgcn_mfma_f32_16x16x32_bf16(Al1, Bh[1], ab, 0, 0, 0);

#pragma unroll
        for (int r = 0; r < 4; ++r) {
            float dd = e2v[r] - 2.f * (aa[r] + ab[r]);
            int   id = codebase + quad * 4 + r;
            bool  c1 = dd < f1;
            bool  c2 = dd < f2_;
            float nf2 = c1 ? f1 : (c2 ? dd : f2_);
            int   ni2 = c1 ? i1 : (c2 ? id : i2_);
            f1  = c1 ? dd : f1;
            i1  = c1 ? id : i1;
            f2_ = nf2;
            i2_ = ni2;
        }
    }

    // ---- cross-quad butterfly merge (lanes {c,c+16,c+32,c+48} same vector) -
#pragma unroll
    for (int delta = 16; delta <= 32; delta <<= 1) {
        float of1 = __shfl_xor(f1, delta, 64);
        int   oi1 = __shfl_xor(i1, delta, 64);
        float of2 = __shfl_xor(f2_, delta, 64);
        int   oi2 = __shfl_xor(i2_, delta, 64);
        bool o1_first = (of1 < f1) || (of1 == f1 && oi1 < i1);
        if (o1_first) {
            bool keep = (f1 < of2) || (f1 == of2 && i1 < oi2);
            f2_ = keep ? f1 : of2;
            i2_ = keep ? i1 : oi2;
            f1 = of1; i1 = oi1;
        } else {
            bool o1_second = (of1 < f2_) || (of1 == f2_ && oi1 < i2_);
            if (o1_second) { f2_ = of1; i2_ = oi1; }
        }
    }
    if (quad == 0) {   // lanes 0..15 publish per (vector, code-half)
        int vloc = vgrp * 16 + l16;
        s_f1[chalf][vloc] = f1;  s_i1[chalf][vloc] = i1;
        s_f2[chalf][vloc] = f2_; s_i2[chalf][vloc] = i2_;
    }
    __syncthreads();

    // ---- final merge across code-halves + fp64 tie re-resolve --------------
    if (tid < 32) {
        const int v = tid;
        float F1 = s_f1[0][v], F2 = s_f2[0][v];
        int   I1 = s_i1[0][v], I2 = s_i2[0][v];
        float of1 = s_f1[1][v], of2 = s_f2[1][v];
        int   oi1 = s_i1[1][v], oi2 = s_i2[1][v];
        bool o1_first = (of1 < F1) || (of1 == F1 && oi1 < I1);
        if (o1_first) {
            bool keep = (F1 < of2) || (F1 == of2 && I1 < oi2);
            F2 = keep ? F1 : of2;  I2 = keep ? I1 : oi2;
            F1 = of1; I1 = oi1;
        } else if ((of1 < F2) || (of1 == F2 && oi1 < I2)) {
            F2 = of1; I2 = oi1;
        }
        int win = I1;
        if (F2 - F1 < TAU) {   // exact fp64 re-resolution of the two candidates
            const float* xr = xb + nbase + v;
            const float* r1 = cb + (size_t)I1 * DIM;
            const float* r2 = cb + (size_t)I2 * DIM;
            double q1 = 0.0, s1 = 0.0, q2 = 0.0, s2 = 0.0;
            for (int d = 0; d < DIM; ++d) {
                double xd = (double)xr[(size_t)d * 1024];
                double e1 = (double)r1[d], e2v2 = (double)r2[d];
                q1 += e1 * e1;   s1 += xd * e1;
                q2 += e2v2 * e2v2; s2 += xd * e2v2;
            }
            double D1 = q1 - 2.0 * s1, D2 = q2 - 2.0 * s2;
            if (D2 < D1 || (D2 == D1 && I2 < I1)) win = I2;
        }
        s_win[v] = win;
    }
    __syncthreads();

    // ---- output: out[b, d, nbase+n] = cb[win[n]][d], coalesced over n ------
    {
        const int n    = tid & 31;            // 32 vectors
        const int dgrp = tid >> 5;            // 8 groups of 8 d
        const float4* crow = (const float4*)(cb + (size_t)s_win[n] * DIM);
        float* op = out + (size_t)b * 65536 + nbase + n;
#pragma unroll
        for (int i = 0; i < 2; ++i) {
            const int d0 = dgrp * 8 + i * 4;
            float4 val = crow[d0 >> 2];
            op[(size_t)(d0 + 0) * 1024] = val.x;
            op[(size_t)(d0 + 1) * 1024] = val.y;
            op[(size_t)(d0 + 2) * 1024] = val.z;
            op[(size_t)(d0 + 3) * 1024] = val.w;
        }
    }
}

extern "C" void kernel_launch(void* const* d_in, const int* in_sizes, int n_in,
                              void* d_out, int out_size, void* d_ws, size_t ws_size,
                              hipStream_t stream) {
    const float* x  = (const float*)d_in[0];   // (64, 64, 32, 32) fp32
    const float* cb = (const float*)d_in[1];   // (512, 64) fp32
    float* out = (float*)d_out;

    // workspace: cb_hi (64KB) | cb_lo (64KB) | e2 (2KB)
    unsigned short* cbh = (unsigned short*)d_ws;
    unsigned short* cbl = cbh + KCODES * DIM;
    float*          e2  = (float*)(cbl + KCODES * DIM);

    prep_kernel<<<KCODES, 64, 0, stream>>>(cb, cbh, cbl, e2);
    vq_main<<<NVEC / 32, 256, 0, stream>>>(x, cb, cbh, cbl, e2, out);
}

// Round 5
// 134.097 us; speedup vs baseline: 1.0490x; 1.0490x over previous
//
#include <hip/hip_runtime.h>

#define KCODES 512
#define DIM    64
#define NVEC   65536          // 64 * 32 * 32
#define TAU    0.05f          // near-tie trigger in dist/2 units (fp32 err ~3e-3)

typedef __attribute__((ext_vector_type(8))) short   short8;  // 8 bf16 = 4 VGPRs
typedef __attribute__((ext_vector_type(4))) float   f32x4;

static __device__ __forceinline__ unsigned f2bfu(float f) {  // fp32 -> bf16 RNE
    unsigned u = __builtin_bit_cast(unsigned, f);
    u += 0x7fffu + ((u >> 16) & 1u);
    return u >> 16;
}

// ---------------------------------------------------------------------------
// Prep: split codebook into bf16 hi(trunc)/lo(RNE of residual); e2q[k] =
// ||e_k||^2/2 + 256 (fp64 reduce). One 64-thread block per code.
// ---------------------------------------------------------------------------
__global__ void prep_kernel(const float* __restrict__ cb,
                            unsigned short* __restrict__ cbh,
                            unsigned short* __restrict__ cbl,
                            float* __restrict__ e2q) {
    const int k = blockIdx.x, d = threadIdx.x;
    const int e = k * DIM + d;
    float v = cb[e];
    unsigned u = __builtin_bit_cast(unsigned, v);
    float hi = __builtin_bit_cast(float, u & 0xFFFF0000u);
    cbh[e] = (unsigned short)(u >> 16);
    cbl[e] = (unsigned short)f2bfu(v - hi);
    double p = (double)v * (double)v;
#pragma unroll
    for (int off = 32; off > 0; off >>= 1) p += __shfl_down(p, off, 64);
    if (d == 0) e2q[k] = (float)(0.5 * p + 256.0);
}

// ---------------------------------------------------------------------------
// Main: block = 64 vectors, 4 waves. Wave: vhalf (32 vecs, 2 n-tiles) x
// chalf (256 codes, 16 tiles). A (codebook bf16 hi/lo) register-double-
// buffered from L2. acc init = e2/2+256, B = -x  =>  acc = dist/2+256-x2/2
// (per-vector constant offset; ranking preserved). Exact fp32 top-2 with
// index tracking; fp64 re-resolve of both candidates on near-tie.
// ---------------------------------------------------------------------------
__launch_bounds__(256, 4)
__global__ void vq_main(const float* __restrict__ x,
                        const float* __restrict__ cb,
                        const unsigned short* __restrict__ cbh,
                        const unsigned short* __restrict__ cbl,
                        const float* __restrict__ e2q,
                        float* __restrict__ out) {
    __shared__ float s_f1[2][64], s_f2[2][64];
    __shared__ int   s_i1[2][64], s_i2[2][64];
    __shared__ int   s_c1[64], s_c2[64], s_flag[64], s_win[64];

    const int tid   = threadIdx.x;
    const int wave  = tid >> 6;
    const int lane  = tid & 63;
    const int vhalf = wave >> 1;
    const int chalf = wave & 1;
    const int quad  = lane >> 4;
    const int l16   = lane & 15;

    const int v0    = blockIdx.x * 64;
    const int b     = v0 >> 10;
    const int nbase = v0 & 1023;
    const float* xb = x + (size_t)b * 65536;

    // ---- B fragments of NEGATED x: B[k=quad*8+j+32ko][n=l16], hi/lo --------
    short8 Bh[2][2], Bl[2][2];
#pragma unroll
    for (int nt = 0; nt < 2; ++nt) {
        const int n_g = nbase + vhalf * 32 + nt * 16 + l16;
#pragma unroll
        for (int ko = 0; ko < 2; ++ko) {
#pragma unroll
            for (int j = 0; j < 8; ++j) {
                const int d = quad * 8 + j + ko * 32;
                float f = -xb[(size_t)d * 1024 + n_g];
                unsigned u = __builtin_bit_cast(unsigned, f);
                float hi = __builtin_bit_cast(float, u & 0xFFFF0000u);
                Bh[nt][ko][j] = (short)(u >> 16);
                Bl[nt][ko][j] = (short)f2bfu(f - hi);
            }
        }
    }

    float f1[2] = {1e30f, 1e30f}, f2_[2] = {1e30f, 1e30f};
    int   i1[2] = {0, 0},         i2_[2] = {0, 0};

    const unsigned lanoff = (unsigned)(l16 * DIM + quad * 8);  // elements
    const int cb0 = chalf * 256;
    short8 Ah0 = *(const short8*)(cbh + (size_t)cb0 * DIM + lanoff);
    short8 Ah1 = *(const short8*)(cbh + (size_t)cb0 * DIM + lanoff + 32);
    short8 Al0 = *(const short8*)(cbl + (size_t)cb0 * DIM + lanoff);
    short8 Al1 = *(const short8*)(cbl + (size_t)cb0 * DIM + lanoff + 32);
    f32x4  e2v = *(const f32x4*)(e2q + cb0 + quad * 4);

#pragma unroll
    for (int t = 0; t < 16; ++t) {
        const int cbase = cb0 + t * 16;
        const int cnext = cb0 + (t < 15 ? t + 1 : t) * 16;
        // register double-buffer: prefetch next tile's A fragments + e2
        short8 nAh0 = *(const short8*)(cbh + (size_t)cnext * DIM + lanoff);
        short8 nAh1 = *(const short8*)(cbh + (size_t)cnext * DIM + lanoff + 32);
        short8 nAl0 = *(const short8*)(cbl + (size_t)cnext * DIM + lanoff);
        short8 nAl1 = *(const short8*)(cbl + (size_t)cnext * DIM + lanoff + 32);
        f32x4  ne2  = *(const f32x4*)(e2q + cnext + quad * 4);

#pragma unroll
        for (int nt = 0; nt < 2; ++nt) {
            f32x4 acc = e2v;   // = e2/2 + 256; with B = -x: acc -> dist-rank
            acc = __builtin_amdgcn_mfma_f32_16x16x32_bf16(Ah0, Bh[nt][0], acc, 0, 0, 0);
            acc = __builtin_amdgcn_mfma_f32_16x16x32_bf16(Ah1, Bh[nt][1], acc, 0, 0, 0);
            acc = __builtin_amdgcn_mfma_f32_16x16x32_bf16(Ah0, Bl[nt][0], acc, 0, 0, 0);
            acc = __builtin_amdgcn_mfma_f32_16x16x32_bf16(Ah1, Bl[nt][1], acc, 0, 0, 0);
            acc = __builtin_amdgcn_mfma_f32_16x16x32_bf16(Al0, Bh[nt][0], acc, 0, 0, 0);
            acc = __builtin_amdgcn_mfma_f32_16x16x32_bf16(Al1, Bh[nt][1], acc, 0, 0, 0);
#pragma unroll
            for (int r = 0; r < 4; ++r) {
                float dd = acc[r];
                int   id = cbase + quad * 4 + r;
                bool  c1 = dd < f1[nt];           // strict: earlier id wins
                bool  c2 = dd < f2_[nt];
                float nf2 = c1 ? f1[nt] : (c2 ? dd : f2_[nt]);
                int   ni2 = c1 ? i1[nt] : (c2 ? id : i2_[nt]);
                f1[nt]  = c1 ? dd : f1[nt];
                i1[nt]  = c1 ? id : i1[nt];
                f2_[nt] = nf2;
                i2_[nt] = ni2;
            }
        }
        Ah0 = nAh0; Ah1 = nAh1; Al0 = nAl0; Al1 = nAl1; e2v = ne2;
    }

    // ---- cross-quad butterfly merge (lanes {c,c+16,c+32,c+48} same vecs) ---
#pragma unroll
    for (int nt = 0; nt < 2; ++nt) {
        float F1 = f1[nt], F2 = f2_[nt];
        int   I1 = i1[nt], I2 = i2_[nt];
#pragma unroll
        for (int delta = 16; delta <= 32; delta <<= 1) {
            float of1 = __shfl_xor(F1, delta, 64);
            int   oi1 = __shfl_xor(I1, delta, 64);
            float of2 = __shfl_xor(F2, delta, 64);
            int   oi2 = __shfl_xor(I2, delta, 64);
            bool o1_first = (of1 < F1) || (of1 == F1 && oi1 < I1);
            if (o1_first) {
                bool keep = (F1 < of2) || (F1 == of2 && I1 < oi2);
                F2 = keep ? F1 : of2;
                I2 = keep ? I1 : oi2;
                F1 = of1; I1 = oi1;
            } else {
                bool o1_second = (of1 < F2) || (of1 == F2 && oi1 < I2);
                if (o1_second) { F2 = of1; I2 = oi1; }
            }
        }
        if (quad == 0) {   // lanes 0..15 publish per (vector, code-half)
            int vloc = vhalf * 32 + nt * 16 + l16;
            s_f1[chalf][vloc] = F1; s_i1[chalf][vloc] = I1;
            s_f2[chalf][vloc] = F2; s_i2[chalf][vloc] = I2;
        }
    }
    __syncthreads();

    // ---- merge code-halves; default winner + near-tie flag -----------------
    if (tid < 64) {
        float F1 = s_f1[0][tid], F2 = s_f2[0][tid];
        int   I1 = s_i1[0][tid], I2 = s_i2[0][tid];
        float of1 = s_f1[1][tid], of2 = s_f2[1][tid];
        int   oi1 = s_i1[1][tid], oi2 = s_i2[1][tid];
        bool o1_first = (of1 < F1) || (of1 == F1 && oi1 < I1);
        if (o1_first) {
            bool keep = (F1 < of2) || (F1 == of2 && I1 < oi2);
            F2 = keep ? F1 : of2;  I2 = keep ? I1 : oi2;
            F1 = of1; I1 = oi1;
        } else if ((of1 < F2) || (of1 == F2 && oi1 < I2)) {
            F2 = of1; I2 = oi1;
        }
        s_win[tid]  = I1;
        s_c1[tid]   = I1;
        s_c2[tid]   = I2;
        s_flag[tid] = (F2 - F1) < TAU;
    }
    __syncthreads();

    // ---- parallel fp64 re-resolve: 4 lanes per vector, both candidates -----
    {
        const int vec = tid >> 2, sub = tid & 3;
        if (s_flag[vec]) {
            const int i1c = s_c1[vec], i2c = s_c2[vec];
            const float* xr = xb + nbase + vec;
            const float* r1 = cb + (size_t)i1c * DIM;
            const float* r2 = cb + (size_t)i2c * DIM;
            double D1 = 0.0, D2 = 0.0;
#pragma unroll 4
            for (int i = 0; i < 16; ++i) {
                const int d = sub + 4 * i;
                double xd = (double)xr[(size_t)d * 1024];
                double t1 = xd - (double)r1[d]; D1 += t1 * t1;
                double t2 = xd - (double)r2[d]; D2 += t2 * t2;
            }
            D1 += __shfl_down(D1, 2, 64); D1 += __shfl_down(D1, 1, 64);
            D2 += __shfl_down(D2, 2, 64); D2 += __shfl_down(D2, 1, 64);
            if (sub == 0) {
                if (D2 < D1 || (D2 == D1 && i2c < i1c)) s_win[vec] = i2c;
            }
        }
    }
    __syncthreads();

    // ---- output: out[b, d, nbase+n] = cb[win[n]][d], coalesced over n ------
    {
        const int n    = tid & 63;
        const int dgrp = tid >> 6;
        const float4* crow = (const float4*)(cb + (size_t)s_win[n] * DIM);
        float* op = out + (size_t)b * 65536 + nbase + n;
#pragma unroll
        for (int i = 0; i < 4; ++i) {
            const int d0 = dgrp * 16 + i * 4;
            float4 val = crow[d0 >> 2];
            op[(size_t)(d0 + 0) * 1024] = val.x;
            op[(size_t)(d0 + 1) * 1024] = val.y;
            op[(size_t)(d0 + 2) * 1024] = val.z;
            op[(size_t)(d0 + 3) * 1024] = val.w;
        }
    }
}

extern "C" void kernel_launch(void* const* d_in, const int* in_sizes, int n_in,
                              void* d_out, int out_size, void* d_ws, size_t ws_size,
                              hipStream_t stream) {
    const float* x  = (const float*)d_in[0];   // (64, 64, 32, 32) fp32
    const float* cb = (const float*)d_in[1];   // (512, 64) fp32
    float* out = (float*)d_out;

    // workspace: cb_hi (64KB) | cb_lo (64KB) | e2q (2KB)
    unsigned short* cbh = (unsigned short*)d_ws;
    unsigned short* cbl = cbh + KCODES * DIM;
    float*          e2q = (float*)(cbl + KCODES * DIM);

    prep_kernel<<<KCODES, 64, 0, stream>>>(cb, cbh, cbl, e2q);
    vq_main<<<NVEC / 64, 256, 0, stream>>>(x, cb, cbh, cbl, e2q, out);
}

// Round 6
// 108.187 us; speedup vs baseline: 1.3002x; 1.2395x over previous
//
#include <hip/hip_runtime.h>

#define KCODES 512
#define DIM    64
#define NVEC   65536          // 64 * 32 * 32
#define TAU    0.05f          // near-tie trigger in dist/2 units (fp32 err ~3e-3)

typedef __attribute__((ext_vector_type(8))) short   short8;  // 8 bf16 = 4 VGPRs
typedef __attribute__((ext_vector_type(4))) float   f32x4;

static __device__ __forceinline__ unsigned f2bfu(float f) {  // fp32 -> bf16 RNE
    unsigned u = __builtin_bit_cast(unsigned, f);
    u += 0x7fffu + ((u >> 16) & 1u);
    return u >> 16;
}

// ---------------------------------------------------------------------------
// Prep: split codebook into bf16 hi(trunc)/lo(RNE of residual); e2q[k] =
// ||e_k||^2/2 + 256 (fp64 reduce). One 64-thread block per code.
// ---------------------------------------------------------------------------
__global__ void prep_kernel(const float* __restrict__ cb,
                            unsigned short* __restrict__ cbh,
                            unsigned short* __restrict__ cbl,
                            float* __restrict__ e2q) {
    const int k = blockIdx.x, d = threadIdx.x;
    const int e = k * DIM + d;
    float v = cb[e];
    unsigned u = __builtin_bit_cast(unsigned, v);
    float hi = __builtin_bit_cast(float, u & 0xFFFF0000u);
    cbh[e] = (unsigned short)(u >> 16);
    cbl[e] = (unsigned short)f2bfu(v - hi);
    double p = (double)v * (double)v;
#pragma unroll
    for (int off = 32; off > 0; off >>= 1) p += __shfl_down(p, off, 64);
    if (d == 0) e2q[k] = (float)(0.5 * p + 256.0);
}

// ---------------------------------------------------------------------------
// Main: block = 64 vectors, 4 waves. Wave: vhalf (32 vecs, 2 n-tiles) x
// chalf (256 codes, 16 tiles). A (codebook bf16 hi/lo) register-double-
// buffered from L2; t-loop pinned to unroll 2 so live range stays ~2 tiles
// (full unroll => load hoisting => 128-reg blowout => scratch spill, R5).
// acc init = e2/2+256, B = -x  =>  acc = dist/2 + 256 - x2/2 (rank-safe).
// Exact fp32 top-2 w/ index; fp64 re-resolve of both candidates on near-tie.
// ---------------------------------------------------------------------------
__launch_bounds__(256, 4)
__global__ void vq_main(const float* __restrict__ x,
                        const float* __restrict__ cb,
                        const unsigned short* __restrict__ cbh,
                        const unsigned short* __restrict__ cbl,
                        const float* __restrict__ e2q,
                        float* __restrict__ out) {
    __shared__ float s_f1[2][64], s_f2[2][64];
    __shared__ int   s_i1[2][64], s_i2[2][64];
    __shared__ int   s_c1[64], s_c2[64], s_flag[64], s_win[64];

    const int tid   = threadIdx.x;
    const int wave  = tid >> 6;
    const int lane  = tid & 63;
    const int vhalf = wave >> 1;
    const int chalf = wave & 1;
    const int quad  = lane >> 4;
    const int l16   = lane & 15;

    const int v0    = blockIdx.x * 64;
    const int b     = v0 >> 10;
    const int nbase = v0 & 1023;
    const float* xb = x + (size_t)b * 65536;

    // ---- B fragments of NEGATED x: B[k=quad*8+j+32ko][n=l16], hi/lo --------
    short8 Bh[2][2], Bl[2][2];
#pragma unroll
    for (int nt = 0; nt < 2; ++nt) {
        const int n_g = nbase + vhalf * 32 + nt * 16 + l16;
#pragma unroll
        for (int ko = 0; ko < 2; ++ko) {
#pragma unroll
            for (int j = 0; j < 8; ++j) {
                const int d = quad * 8 + j + ko * 32;
                float f = -xb[(size_t)d * 1024 + n_g];
                unsigned u = __builtin_bit_cast(unsigned, f);
                float hi = __builtin_bit_cast(float, u & 0xFFFF0000u);
                Bh[nt][ko][j] = (short)(u >> 16);
                Bl[nt][ko][j] = (short)f2bfu(f - hi);
            }
        }
    }

    float f1[2] = {1e30f, 1e30f}, f2_[2] = {1e30f, 1e30f};
    int   i1[2] = {0, 0},         i2_[2] = {0, 0};

    const unsigned lanoff = (unsigned)(l16 * DIM + quad * 8);  // elements
    const int cb0 = chalf * 256;
    short8 Ah0 = *(const short8*)(cbh + (size_t)cb0 * DIM + lanoff);
    short8 Ah1 = *(const short8*)(cbh + (size_t)cb0 * DIM + lanoff + 32);
    short8 Al0 = *(const short8*)(cbl + (size_t)cb0 * DIM + lanoff);
    short8 Al1 = *(const short8*)(cbl + (size_t)cb0 * DIM + lanoff + 32);
    f32x4  e2v = *(const f32x4*)(e2q + cb0 + quad * 4);

#pragma unroll 2
    for (int t = 0; t < 16; ++t) {
        const int cbase = cb0 + t * 16;
        const int cnext = cb0 + (t < 15 ? t + 1 : t) * 16;
        // register double-buffer: prefetch next tile's A fragments + e2
        short8 nAh0 = *(const short8*)(cbh + (size_t)cnext * DIM + lanoff);
        short8 nAh1 = *(const short8*)(cbh + (size_t)cnext * DIM + lanoff + 32);
        short8 nAl0 = *(const short8*)(cbl + (size_t)cnext * DIM + lanoff);
        short8 nAl1 = *(const short8*)(cbl + (size_t)cnext * DIM + lanoff + 32);
        f32x4  ne2  = *(const f32x4*)(e2q + cnext + quad * 4);

#pragma unroll
        for (int nt = 0; nt < 2; ++nt) {
            f32x4 acc = e2v;   // = e2/2 + 256; with B = -x: acc -> dist-rank
            acc = __builtin_amdgcn_mfma_f32_16x16x32_bf16(Ah0, Bh[nt][0], acc, 0, 0, 0);
            acc = __builtin_amdgcn_mfma_f32_16x16x32_bf16(Ah1, Bh[nt][1], acc, 0, 0, 0);
            acc = __builtin_amdgcn_mfma_f32_16x16x32_bf16(Ah0, Bl[nt][0], acc, 0, 0, 0);
            acc = __builtin_amdgcn_mfma_f32_16x16x32_bf16(Ah1, Bl[nt][1], acc, 0, 0, 0);
            acc = __builtin_amdgcn_mfma_f32_16x16x32_bf16(Al0, Bh[nt][0], acc, 0, 0, 0);
            acc = __builtin_amdgcn_mfma_f32_16x16x32_bf16(Al1, Bh[nt][1], acc, 0, 0, 0);
#pragma unroll
            for (int r = 0; r < 4; ++r) {
                float dd = acc[r];
                int   id = cbase + quad * 4 + r;
                bool  c1 = dd < f1[nt];           // strict: earlier id wins
                bool  c2 = dd < f2_[nt];
                float nf2 = c1 ? f1[nt] : (c2 ? dd : f2_[nt]);
                int   ni2 = c1 ? i1[nt] : (c2 ? id : i2_[nt]);
                f1[nt]  = c1 ? dd : f1[nt];
                i1[nt]  = c1 ? id : i1[nt];
                f2_[nt] = nf2;
                i2_[nt] = ni2;
            }
        }
        Ah0 = nAh0; Ah1 = nAh1; Al0 = nAl0; Al1 = nAl1; e2v = ne2;
    }

    // ---- cross-quad butterfly merge (lanes {c,c+16,c+32,c+48} same vecs) ---
#pragma unroll
    for (int nt = 0; nt < 2; ++nt) {
        float F1 = f1[nt], F2 = f2_[nt];
        int   I1 = i1[nt], I2 = i2_[nt];
#pragma unroll
        for (int delta = 16; delta <= 32; delta <<= 1) {
            float of1 = __shfl_xor(F1, delta, 64);
            int   oi1 = __shfl_xor(I1, delta, 64);
            float of2 = __shfl_xor(F2, delta, 64);
            int   oi2 = __shfl_xor(I2, delta, 64);
            bool o1_first = (of1 < F1) || (of1 == F1 && oi1 < I1);
            if (o1_first) {
                bool keep = (F1 < of2) || (F1 == of2 && I1 < oi2);
                F2 = keep ? F1 : of2;
                I2 = keep ? I1 : oi2;
                F1 = of1; I1 = oi1;
            } else {
                bool o1_second = (of1 < F2) || (of1 == F2 && oi1 < I2);
                if (o1_second) { F2 = of1; I2 = oi1; }
            }
        }
        if (quad == 0) {   // lanes 0..15 publish per (vector, code-half)
            int vloc = vhalf * 32 + nt * 16 + l16;
            s_f1[chalf][vloc] = F1; s_i1[chalf][vloc] = I1;
            s_f2[chalf][vloc] = F2; s_i2[chalf][vloc] = I2;
        }
    }
    __syncthreads();

    // ---- merge code-halves; default winner + near-tie flag -----------------
    if (tid < 64) {
        float F1 = s_f1[0][tid], F2 = s_f2[0][tid];
        int   I1 = s_i1[0][tid], I2 = s_i2[0][tid];
        float of1 = s_f1[1][tid], of2 = s_f2[1][tid];
        int   oi1 = s_i1[1][tid], oi2 = s_i2[1][tid];
        bool o1_first = (of1 < F1) || (of1 == F1 && oi1 < I1);
        if (o1_first) {
            bool keep = (F1 < of2) || (F1 == of2 && I1 < oi2);
            F2 = keep ? F1 : of2;  I2 = keep ? I1 : oi2;
            F1 = of1; I1 = oi1;
        } else if ((of1 < F2) || (of1 == F2 && oi1 < I2)) {
            F2 = of1; I2 = oi1;
        }
        s_win[tid]  = I1;
        s_c1[tid]   = I1;
        s_c2[tid]   = I2;
        s_flag[tid] = (F2 - F1) < TAU;
    }
    __syncthreads();

    // ---- parallel fp64 re-resolve: 4 lanes per vector, both candidates -----
    {
        const int vec = tid >> 2, sub = tid & 3;
        if (s_flag[vec]) {
            const int i1c = s_c1[vec], i2c = s_c2[vec];
            const float* xr = xb + nbase + vec;
            const float* r1 = cb + (size_t)i1c * DIM;
            const float* r2 = cb + (size_t)i2c * DIM;
            double D1 = 0.0, D2 = 0.0;
#pragma unroll 4
            for (int i = 0; i < 16; ++i) {
                const int d = sub + 4 * i;
                double xd = (double)xr[(size_t)d * 1024];
                double t1 = xd - (double)r1[d]; D1 += t1 * t1;
                double t2 = xd - (double)r2[d]; D2 += t2 * t2;
            }
            D1 += __shfl_down(D1, 2, 64); D1 += __shfl_down(D1, 1, 64);
            D2 += __shfl_down(D2, 2, 64); D2 += __shfl_down(D2, 1, 64);
            if (sub == 0) {
                if (D2 < D1 || (D2 == D1 && i2c < i1c)) s_win[vec] = i2c;
            }
        }
    }
    __syncthreads();

    // ---- output: out[b, d, nbase+n] = cb[win[n]][d], coalesced over n ------
    {
        const int n    = tid & 63;
        const int dgrp = tid >> 6;
        const float4* crow = (const float4*)(cb + (size_t)s_win[n] * DIM);
        float* op = out + (size_t)b * 65536 + nbase + n;
#pragma unroll
        for (int i = 0; i < 4; ++i) {
            const int d0 = dgrp * 16 + i * 4;
            float4 val = crow[d0 >> 2];
            op[(size_t)(d0 + 0) * 1024] = val.x;
            op[(size_t)(d0 + 1) * 1024] = val.y;
            op[(size_t)(d0 + 2) * 1024] = val.z;
            op[(size_t)(d0 + 3) * 1024] = val.w;
        }
    }
}

extern "C" void kernel_launch(void* const* d_in, const int* in_sizes, int n_in,
                              void* d_out, int out_size, void* d_ws, size_t ws_size,
                              hipStream_t stream) {
    const float* x  = (const float*)d_in[0];   // (64, 64, 32, 32) fp32
    const float* cb = (const float*)d_in[1];   // (512, 64) fp32
    float* out = (float*)d_out;

    // workspace: cb_hi (64KB) | cb_lo (64KB) | e2q (2KB)
    unsigned short* cbh = (unsigned short*)d_ws;
    unsigned short* cbl = cbh + KCODES * DIM;
    float*          e2q = (float*)(cbl + KCODES * DIM);

    prep_kernel<<<KCODES, 64, 0, stream>>>(cb, cbh, cbl, e2q);
    vq_main<<<NVEC / 64, 256, 0, stream>>>(x, cb, cbh, cbl, e2q, out);
}

// Round 7
// 96.258 us; speedup vs baseline: 1.4613x; 1.1239x over previous
//
#include <hip/hip_runtime.h>

#define KCODES 512
#define DIM    64
#define NVEC   65536          // 64 * 32 * 32
#define TAU    0.05f          // near-tie trigger in dist/2 units (fp32 err ~3e-3)

typedef __attribute__((ext_vector_type(8))) short   short8;  // 8 bf16 = 4 VGPRs
typedef __attribute__((ext_vector_type(4))) float   f32x4;

static __device__ __forceinline__ unsigned f2bfu(float f) {  // fp32 -> bf16 RNE
    unsigned u = __builtin_bit_cast(unsigned, f);
    u += 0x7fffu + ((u >> 16) & 1u);
    return u >> 16;
}

// ---------------------------------------------------------------------------
// Prep: split codebook into bf16 hi(trunc)/lo(RNE of residual); e2q[k] =
// ||e_k||^2/2 + 256 (fp64 reduce). One 64-thread block per code.
// ---------------------------------------------------------------------------
__global__ void prep_kernel(const float* __restrict__ cb,
                            unsigned short* __restrict__ cbh,
                            unsigned short* __restrict__ cbl,
                            float* __restrict__ e2q) {
    const int k = blockIdx.x, d = threadIdx.x;
    const int e = k * DIM + d;
    float v = cb[e];
    unsigned u = __builtin_bit_cast(unsigned, v);
    float hi = __builtin_bit_cast(float, u & 0xFFFF0000u);
    cbh[e] = (unsigned short)(u >> 16);
    cbl[e] = (unsigned short)f2bfu(v - hi);
    double p = (double)v * (double)v;
#pragma unroll
    for (int off = 32; off > 0; off >>= 1) p += __shfl_down(p, off, 64);
    if (d == 0) e2q[k] = (float)(0.5 * p + 256.0);
}

// ---------------------------------------------------------------------------
// Main: block = 128 vectors, 4 waves; wave w owns 32 vectors (2 n-tiles) and
// ranks ALL 512 codes. Codebook (bf16 hi/lo) staged block-wide in LDS, 64
// codes/step, double-buffered: global->reg before compute, ds_write after,
// one barrier per step. LDS A layout [dim-group][code][8] so frag reads are
// b128 at LDS BW floor. acc init = e2/2+256, B = -x => acc = rank-safe dist.
// Exact fp32 top-2 w/ index; fp64 re-resolve of both candidates on near-tie.
// ---------------------------------------------------------------------------
__launch_bounds__(256, 2)
__global__ void vq_main(const float* __restrict__ x,
                        const float* __restrict__ cb,
                        const unsigned short* __restrict__ cbh,
                        const unsigned short* __restrict__ cbl,
                        const float* __restrict__ e2q,
                        float* __restrict__ out) {
    __shared__ unsigned short sAh[2][4096];   // [buf][qd*64+c][8]  8 KB each
    __shared__ unsigned short sAl[2][4096];
    __shared__ float sE2[KCODES];
    __shared__ int   s_i1[128], s_i2[128], s_flag[128], s_win[128];

    const int tid  = threadIdx.x;
    const int wave = tid >> 6;
    const int lane = tid & 63;
    const int quad = lane >> 4;
    const int l16  = lane & 15;

    const int v0    = blockIdx.x * 128;
    const int b     = v0 >> 10;
    const int nbase = v0 & 1023;
    const float* xb = x + (size_t)b * 65536;

    // ---- stage step 0 into regs (latency hidden behind B-frag build) -------
    short8 stg[4];
#pragma unroll
    for (int r = 0; r < 4; ++r) {
        const int idx = tid + r * 256;        // [0,1024): <512 hi, >=512 lo
        const int q  = idx & 511;
        const int c  = q >> 3, qd = q & 7;
        const unsigned short* src = (idx < 512 ? cbh : cbl) + (size_t)c * 64 + qd * 8;
        stg[r] = *(const short8*)src;
    }

    // ---- B fragments of NEGATED x: B[k=quad*8+j+32ko][n=l16], hi/lo --------
    short8 Bh[2][2], Bl[2][2];
#pragma unroll
    for (int nt = 0; nt < 2; ++nt) {
        const int n_g = nbase + wave * 32 + nt * 16 + l16;
#pragma unroll
        for (int ko = 0; ko < 2; ++ko) {
#pragma unroll
            for (int j = 0; j < 8; ++j) {
                const int d = quad * 8 + j + ko * 32;
                float f = -xb[(size_t)d * 1024 + n_g];
                unsigned u = __builtin_bit_cast(unsigned, f);
                float hi = __builtin_bit_cast(float, u & 0xFFFF0000u);
                Bh[nt][ko][j] = (short)(u >> 16);
                Bl[nt][ko][j] = (short)f2bfu(f - hi);
            }
        }
    }

    // ---- stage e2 and step 0 into LDS --------------------------------------
    if (tid < 128) *(f32x4*)(sE2 + tid * 4) = *(const f32x4*)(e2q + tid * 4);
#pragma unroll
    for (int r = 0; r < 4; ++r) {
        const int idx = tid + r * 256;
        const int q  = idx & 511;
        const int c  = q >> 3, qd = q & 7;
        unsigned short* dst = (idx < 512 ? sAh[0] : sAl[0]) + (qd * 64 + c) * 8;
        *(short8*)dst = stg[r];
    }
    __syncthreads();

    float f1[2] = {1e30f, 1e30f}, f2_[2] = {1e30f, 1e30f};
    int   i1[2] = {0, 0},         i2_[2] = {0, 0};

#pragma unroll 1
    for (int s = 0; s < 8; ++s) {
        // prefetch step s+1 into regs (before compute; hidden)
        if (s < 7) {
#pragma unroll
            for (int r = 0; r < 4; ++r) {
                const int idx = tid + r * 256;
                const int q  = idx & 511;
                const int c  = q >> 3, qd = q & 7;
                const unsigned short* src =
                    (idx < 512 ? cbh : cbl) + (size_t)((s + 1) * 64 + c) * 64 + qd * 8;
                stg[r] = *(const short8*)src;
            }
        }

        // compute on buffer s&1: 4 subtiles of 16 codes
        const unsigned short* bh = sAh[s & 1];
        const unsigned short* bl = sAl[s & 1];
#pragma unroll
        for (int st = 0; st < 4; ++st) {
            const int cbase = s * 64 + st * 16;
            short8 Ah0 = *(const short8*)(bh + ( quad      * 64 + st * 16 + l16) * 8);
            short8 Ah1 = *(const short8*)(bh + ((quad + 4) * 64 + st * 16 + l16) * 8);
            short8 Al0 = *(const short8*)(bl + ( quad      * 64 + st * 16 + l16) * 8);
            short8 Al1 = *(const short8*)(bl + ((quad + 4) * 64 + st * 16 + l16) * 8);
            f32x4  e2v = *(const f32x4*)(sE2 + cbase + quad * 4);

#pragma unroll
            for (int nt = 0; nt < 2; ++nt) {
                f32x4 acc = e2v;   // = e2/2 + 256; with B = -x: rank-safe dist
                acc = __builtin_amdgcn_mfma_f32_16x16x32_bf16(Ah0, Bh[nt][0], acc, 0, 0, 0);
                acc = __builtin_amdgcn_mfma_f32_16x16x32_bf16(Ah1, Bh[nt][1], acc, 0, 0, 0);
                acc = __builtin_amdgcn_mfma_f32_16x16x32_bf16(Ah0, Bl[nt][0], acc, 0, 0, 0);
                acc = __builtin_amdgcn_mfma_f32_16x16x32_bf16(Ah1, Bl[nt][1], acc, 0, 0, 0);
                acc = __builtin_amdgcn_mfma_f32_16x16x32_bf16(Al0, Bh[nt][0], acc, 0, 0, 0);
                acc = __builtin_amdgcn_mfma_f32_16x16x32_bf16(Al1, Bh[nt][1], acc, 0, 0, 0);
#pragma unroll
                for (int r = 0; r < 4; ++r) {
                    float dd = acc[r];
                    int   id = cbase + quad * 4 + r;
                    bool  c1 = dd < f1[nt];           // strict: earlier id wins
                    bool  c2 = dd < f2_[nt];
                    float nf2 = c1 ? f1[nt] : (c2 ? dd : f2_[nt]);
                    int   ni2 = c1 ? i1[nt] : (c2 ? id : i2_[nt]);
                    f1[nt]  = c1 ? dd : f1[nt];
                    i1[nt]  = c1 ? id : i1[nt];
                    f2_[nt] = nf2;
                    i2_[nt] = ni2;
                }
            }
        }

        // publish step s+1 to the other buffer
        if (s < 7) {
#pragma unroll
            for (int r = 0; r < 4; ++r) {
                const int idx = tid + r * 256;
                const int q  = idx & 511;
                const int c  = q >> 3, qd = q & 7;
                unsigned short* dst =
                    (idx < 512 ? sAh[(s + 1) & 1] : sAl[(s + 1) & 1]) + (qd * 64 + c) * 8;
                *(short8*)dst = stg[r];
            }
        }
        __syncthreads();
    }

    // ---- cross-quad butterfly merge; each wave has full-512 top-2 ----------
#pragma unroll
    for (int nt = 0; nt < 2; ++nt) {
        float F1 = f1[nt], F2 = f2_[nt];
        int   I1 = i1[nt], I2 = i2_[nt];
#pragma unroll
        for (int delta = 16; delta <= 32; delta <<= 1) {
            float of1 = __shfl_xor(F1, delta, 64);
            int   oi1 = __shfl_xor(I1, delta, 64);
            float of2 = __shfl_xor(F2, delta, 64);
            int   oi2 = __shfl_xor(I2, delta, 64);
            bool o1_first = (of1 < F1) || (of1 == F1 && oi1 < I1);
            if (o1_first) {
                bool keep = (F1 < of2) || (F1 == of2 && I1 < oi2);
                F2 = keep ? F1 : of2;
                I2 = keep ? I1 : oi2;
                F1 = of1; I1 = oi1;
            } else {
                bool o1_second = (of1 < F2) || (of1 == F2 && oi1 < I2);
                if (o1_second) { F2 = of1; I2 = oi1; }
            }
        }
        if (quad == 0) {   // lanes 0..15 hold final result for their vector
            const int vl = wave * 32 + nt * 16 + l16;
            s_win[vl]  = I1;
            s_i1[vl]   = I1;
            s_i2[vl]   = I2;
            s_flag[vl] = (F2 - F1) < TAU;
        }
    }
    __syncthreads();

    // ---- parallel fp64 re-resolve: 2 lanes per vector, both candidates -----
    {
        const int vec = tid >> 1, sub = tid & 1;
        if (s_flag[vec]) {
            const int i1c = s_i1[vec], i2c = s_i2[vec];
            const float* xr = xb + nbase + vec;
            const float* r1 = cb + (size_t)i1c * DIM;
            const float* r2 = cb + (size_t)i2c * DIM;
            double D1 = 0.0, D2 = 0.0;
#pragma unroll 4
            for (int i = 0; i < 32; ++i) {
                const int d = sub + 2 * i;
                double xd = (double)xr[(size_t)d * 1024];
                double t1 = xd - (double)r1[d]; D1 += t1 * t1;
                double t2 = xd - (double)r2[d]; D2 += t2 * t2;
            }
            D1 += __shfl_down(D1, 1, 64);
            D2 += __shfl_down(D2, 1, 64);
            if (sub == 0) {
                if (D2 < D1 || (D2 == D1 && i2c < i1c)) s_win[vec] = i2c;
            }
        }
    }
    __syncthreads();

    // ---- output: out[b, d, nbase+n] = cb[win[n]][d], coalesced over n ------
    {
        const int n    = tid & 127;           // 128 vectors
        const int dgrp = tid >> 7;            // 2 groups of 32 dims
        const float4* crow = (const float4*)(cb + (size_t)s_win[n] * DIM);
        float* op = out + (size_t)b * 65536 + nbase + n;
#pragma unroll
        for (int i = 0; i < 8; ++i) {
            const int d0 = dgrp * 32 + i * 4;
            float4 val = crow[d0 >> 2];
            op[(size_t)(d0 + 0) * 1024] = val.x;
            op[(size_t)(d0 + 1) * 1024] = val.y;
            op[(size_t)(d0 + 2) * 1024] = val.z;
            op[(size_t)(d0 + 3) * 1024] = val.w;
        }
    }
}

extern "C" void kernel_launch(void* const* d_in, const int* in_sizes, int n_in,
                              void* d_out, int out_size, void* d_ws, size_t ws_size,
                              hipStream_t stream) {
    const float* x  = (const float*)d_in[0];   // (64, 64, 32, 32) fp32
    const float* cb = (const float*)d_in[1];   // (512, 64) fp32
    float* out = (float*)d_out;

    // workspace: cb_hi (64KB) | cb_lo (64KB) | e2q (2KB)
    unsigned short* cbh = (unsigned short*)d_ws;
    unsigned short* cbl = cbh + KCODES * DIM;
    float*          e2q = (float*)(cbl + KCODES * DIM);

    prep_kernel<<<KCODES, 64, 0, stream>>>(cb, cbh, cbl, e2q);
    vq_main<<<NVEC / 128, 256, 0, stream>>>(x, cb, cbh, cbl, e2q, out);
}